// Round 1
// baseline (199.366 us; speedup 1.0000x reference)
//
#include <hip/hip_runtime.h>
#include <math.h>

// DistanceNetwork: out[b,i] = (query[b] . support[b,i]) * rsqrt(max(|support[b,i]|^2, EPS))
// support: [B=2048, CK=256, D=512] fp32, query: [B, D] fp32, out: [B, CK] fp32.
// Memory-bound: must stream 1 GiB of support once. Roofline ~172 us @ 6.3 TB/s.

#define B_DIM  2048
#define CK_DIM 256
#define D_DIM  512
#define EPS_F  1e-10f

__global__ __launch_bounds__(256) void distance_net_kernel(
    const float* __restrict__ support,
    const float* __restrict__ query,
    float* __restrict__ out)
{
    const int b    = blockIdx.x;
    const int tid  = threadIdx.x;
    const int lane = tid & 63;
    const int wave = tid >> 6;   // 4 waves per block

    // Hoist this lane's query fragment into registers: elements [4l..4l+3] and [256+4l..256+4l+3].
    const float4* q4 = reinterpret_cast<const float4*>(query + (size_t)b * D_DIM);
    const float4 qa = q4[lane];
    const float4 qb = q4[64 + lane];

    const float* sup_b = support + (size_t)b * CK_DIM * D_DIM;
    float* out_b = out + (size_t)b * CK_DIM;

    // Each wave handles rows wave, wave+4, ... (64 rows per wave).
    for (int i = wave; i < CK_DIM; i += 4) {
        const float4* s4 = reinterpret_cast<const float4*>(sup_b + (size_t)i * D_DIM);
        // Two contiguous 1 KiB segments per wave -> perfectly coalesced.
        const float4 sa = s4[lane];
        const float4 sb = s4[64 + lane];

        float dot = sa.x * qa.x + sa.y * qa.y + sa.z * qa.z + sa.w * qa.w
                  + sb.x * qb.x + sb.y * qb.y + sb.z * qb.z + sb.w * qb.w;
        float nrm = sa.x * sa.x + sa.y * sa.y + sa.z * sa.z + sa.w * sa.w
                  + sb.x * sb.x + sb.y * sb.y + sb.z * sb.z + sb.w * sb.w;

        // 64-lane butterfly reduction of (dot, nrm).
        #pragma unroll
        for (int off = 32; off >= 1; off >>= 1) {
            dot += __shfl_xor(dot, off);
            nrm += __shfl_xor(nrm, off);
        }

        if (lane == 0) {
            out_b[i] = dot * rsqrtf(fmaxf(nrm, EPS_F));
        }
    }
}

extern "C" void kernel_launch(void* const* d_in, const int* in_sizes, int n_in,
                              void* d_out, int out_size, void* d_ws, size_t ws_size,
                              hipStream_t stream) {
    const float* support = (const float*)d_in[0];
    const float* query   = (const float*)d_in[1];
    float* out           = (float*)d_out;

    dim3 grid(B_DIM);
    dim3 block(256);
    distance_net_kernel<<<grid, block, 0, stream>>>(support, query, out);
}